// Round 1
// 1114.160 us; speedup vs baseline: 1.5798x; 1.5798x over previous
//
#include <hip/hip_runtime.h>
#include <cmath>

#define S_   2048
#define B_   2
#define D_   1024
#define H_   16
#define DH_  64
#define DFF_ 4096
#define E_   4
#define T_   4096
#define SCALE_ 0.125f

typedef __attribute__((ext_vector_type(8))) short short8;
typedef __attribute__((ext_vector_type(4))) float f32x4;
typedef __attribute__((ext_vector_type(4))) unsigned short u16x4;
typedef __attribute__((ext_vector_type(4))) unsigned int u32x4;

static __device__ __forceinline__ unsigned short f2bf(float f) {
  union { float f; unsigned int u; } v; v.f = f;
  unsigned int r = v.u + 0x7FFFu + ((v.u >> 16) & 1u);
  return (unsigned short)(r >> 16);
}

static __device__ __forceinline__ float bf2f(unsigned short u) {
  union { unsigned int u; float f; } v; v.u = (unsigned int)u << 16;
  return v.f;
}

static __device__ __forceinline__ f32x4 mfma16(short8 a, short8 b, f32x4 c) {
  return __builtin_amdgcn_mfma_f32_16x16x32_bf16(a, b, c, 0, 0, 0);
}

// async global->LDS: 16B per lane; LDS dest = wave-uniform base + lane*16.
static __device__ __forceinline__ void gll16(const unsigned short* g, unsigned short* l) {
  __builtin_amdgcn_global_load_lds(
      (const __attribute__((address_space(1))) void*)g,
      (__attribute__((address_space(3))) void*)l, 16, 0, 0);
}

// fast gelu: vv * e^(2u) / (e^(2u)+1), u = 0.797885*(v+0.044715 v^3); max err ~3e-4
static __device__ __forceinline__ float gelu_f(float vv) {
  float u = 0.7978845608f * (vv + 0.044715f * vv * vv * vv);
  u = fminf(fmaxf(u, -9.0f), 9.0f);
  float e2 = __expf(2.0f * u);
  return vv * e2 * (1.0f / (e2 + 1.0f));
}

// ---------------- transpose + fp32->bf16: out[c][r] = bf16(in[r][c]), z-batched ------
// 64-wide in r (output-col dim) so stores are full 128B lines (packed 2xbf16 dwords).
__global__ void transpose_cvt(const float* __restrict__ in, unsigned short* __restrict__ out,
                              int R, int C) {
  __shared__ float t[64][33];
  size_t boff = (size_t)blockIdx.z * R * C;
  in += boff; out += boff;
  int c0 = blockIdx.x * 32, r0 = blockIdx.y * 64;
  for (int i = threadIdx.y; i < 64; i += 8)
    t[i][threadIdx.x] = in[(size_t)(r0 + i) * C + c0 + threadIdx.x];
  __syncthreads();
  for (int i = threadIdx.y; i < 32; i += 8) {
    float v0 = t[2 * threadIdx.x][i], v1 = t[2 * threadIdx.x + 1][i];
    unsigned int pk = (unsigned int)f2bf(v0) | ((unsigned int)f2bf(v1) << 16);
    *(unsigned int*)(&out[(size_t)(c0 + i) * R + r0 + 2 * threadIdx.x]) = pk;
  }
}

__global__ void transpose_cvt_split(const float* __restrict__ in,
    unsigned short* __restrict__ outh, unsigned short* __restrict__ outl, int R, int C) {
  __shared__ float t[64][33];
  int c0 = blockIdx.x * 32, r0 = blockIdx.y * 64;
  for (int i = threadIdx.y; i < 64; i += 8)
    t[i][threadIdx.x] = in[(size_t)(r0 + i) * C + c0 + threadIdx.x];
  __syncthreads();
  for (int i = threadIdx.y; i < 32; i += 8) {
    float v0 = t[2 * threadIdx.x][i], v1 = t[2 * threadIdx.x + 1][i];
    unsigned short h0 = f2bf(v0), h1 = f2bf(v1);
    unsigned int hp = (unsigned int)h0 | ((unsigned int)h1 << 16);
    unsigned int lp = (unsigned int)f2bf(v0 - bf2f(h0)) |
                      ((unsigned int)f2bf(v1 - bf2f(h1)) << 16);
    size_t o = (size_t)(c0 + i) * R + r0 + 2 * threadIdx.x;
    *(unsigned int*)(&outh[o]) = hp;
    *(unsigned int*)(&outl[o]) = lp;
  }
}

// ---------------- block reduce (sum, sumsq) over 256 threads -------------------------
static __device__ __forceinline__ void block_reduce2(float& s, float& s2, float* sh) {
  __syncthreads();
  for (int off = 32; off; off >>= 1) { s += __shfl_down(s, off); s2 += __shfl_down(s2, off); }
  int w = threadIdx.x >> 6;
  if ((threadIdx.x & 63) == 0) { sh[w * 2] = s; sh[w * 2 + 1] = s2; }
  __syncthreads();
  s = sh[0] + sh[2] + sh[4] + sh[6];
  s2 = sh[1] + sh[3] + sh[5] + sh[7];
}

// ---------------- input layernorm: h (f32) + split bf16 ------------------------------
__global__ __launch_bounds__(256) void ln_in_kernel(const float* __restrict__ hid,
    const float* __restrict__ g, const float* __restrict__ b,
    float* __restrict__ h, unsigned short* __restrict__ hbh, unsigned short* __restrict__ hbl) {
  __shared__ float sh[8];
  int t = blockIdx.x, tid = threadIdx.x;
  size_t ro = (size_t)t * D_;
  f32x4 v = ((const f32x4*)(hid + ro))[tid];
  float s = v[0] + v[1] + v[2] + v[3];
  float s2 = v[0]*v[0] + v[1]*v[1] + v[2]*v[2] + v[3]*v[3];
  block_reduce2(s, s2, sh);
  float mean = s * (1.0f / D_);
  float var = s2 * (1.0f / D_) - mean * mean;
  float rstd = rsqrtf(var + 1e-6f);
  f32x4 gv = ((const f32x4*)g)[tid], bv = ((const f32x4*)b)[tid];
  f32x4 y; u16x4 yh, yl;
  for (int c = 0; c < 4; ++c) {
    float z = (v[c] - mean) * rstd * gv[c] + bv[c];
    y[c] = z; yh[c] = f2bf(z); yl[c] = f2bf(z - bf2f(yh[c]));
  }
  ((f32x4*)(h + ro))[tid] = y;
  ((u16x4*)(hbh + ro))[tid] = yh;
  ((u16x4*)(hbl + ro))[tid] = yl;
}

// ---------------- fused: attn-LN + residual + post-LN --------------------------------
__global__ __launch_bounds__(256) void ln_fused_kernel(
    const float* __restrict__ hid, const float* __restrict__ h, const float* __restrict__ ao,
    const float* __restrict__ ga, const float* __restrict__ ba,
    const float* __restrict__ gp, const float* __restrict__ bp,
    float* __restrict__ out, float* __restrict__ x, unsigned short* __restrict__ xb) {
  __shared__ float sh[8];
  int t = blockIdx.x, tid = threadIdx.x;
  size_t ro = (size_t)t * D_;
  f32x4 hv = ((const f32x4*)(h + ro))[tid];
  f32x4 av = ((const f32x4*)(ao + ro))[tid];
  f32x4 a = hv + av;
  float s = a[0] + a[1] + a[2] + a[3];
  float s2 = a[0]*a[0] + a[1]*a[1] + a[2]*a[2] + a[3]*a[3];
  block_reduce2(s, s2, sh);
  float mean = s * (1.0f / D_);
  float var = s2 * (1.0f / D_) - mean * mean;
  float rstd = rsqrtf(var + 1e-5f);
  f32x4 lg = ((const f32x4*)ga)[tid], lb = ((const f32x4*)ba)[tid];
  f32x4 hidv = ((const f32x4*)(hid + ro))[tid];
  f32x4 li;
  for (int c = 0; c < 4; ++c) li[c] = hidv[c] + (a[c] - mean) * rstd * lg[c] + lb[c];
  ((f32x4*)(out + ro))[tid] = li;
  float s3 = li[0] + li[1] + li[2] + li[3];
  float s4 = li[0]*li[0] + li[1]*li[1] + li[2]*li[2] + li[3]*li[3];
  block_reduce2(s3, s4, sh);
  float mean2 = s3 * (1.0f / D_);
  float var2 = s4 * (1.0f / D_) - mean2 * mean2;
  float rstd2 = rsqrtf(var2 + 1e-6f);
  f32x4 g2 = ((const f32x4*)gp)[tid], b2v = ((const f32x4*)bp)[tid];
  f32x4 xv; u16x4 xbv;
  for (int c = 0; c < 4; ++c) { float z = (li[c] - mean2) * rstd2 * g2[c] + b2v[c]; xv[c] = z; xbv[c] = f2bf(z); }
  ((f32x4*)(x + ro))[tid] = xv;
  ((u16x4*)(xb + ro))[tid] = xbv;
}

// ---------------- fused Q+KV split-bf16 GEMM: N = 3072 cols over two outputs ---------
// Epilogue: per-wave 16x64 LDS slabs (stride 72) -> full-line dwordx4 stores.
__global__ __launch_bounds__(256) void qkv_gemm(
    const unsigned short* __restrict__ Ah, const unsigned short* __restrict__ Al,
    const unsigned short* __restrict__ WqTh, const unsigned short* __restrict__ WqTl,
    const unsigned short* __restrict__ WkvTh, const unsigned short* __restrict__ WkvTl,
    unsigned short* __restrict__ qh, unsigned short* __restrict__ ql,
    unsigned short* __restrict__ kvh, unsigned short* __restrict__ kvl) {
  const int K = 1024;
  int m0 = blockIdx.y * 128, n0g = blockIdx.x * 128;
  const unsigned short *Bh, *Bl;
  unsigned short *Ch, *Cl;
  int NC, n0;
  if (n0g < 1024) { Bh = WqTh; Bl = WqTl; Ch = qh; Cl = ql; NC = 1024; n0 = n0g; }
  else { Bh = WkvTh; Bl = WkvTl; Ch = kvh; Cl = kvl; NC = 2048; n0 = n0g - 1024; }
  __shared__ unsigned short pool2[16384];
  unsigned short* Ash = pool2;
  unsigned short* Asl = pool2 + 4096;
  unsigned short* Bsh = pool2 + 8192;
  unsigned short* Bsl = pool2 + 12288;
  int tid = threadIdx.x;
  int lane = tid & 63, w = tid >> 6;
  int quad = lane >> 4, l15 = lane & 15;
  int wm = (w >> 1) * 64, wn = (w & 1) * 64;
  f32x4 acc[4][4];
  for (int i = 0; i < 4; ++i) for (int j = 0; j < 4; ++j) acc[i][j] = 0;
  int rs0 = w * 32 + (lane >> 2), rs1 = rs0 + 16;
  int cofs = (lane & 3) * 8;
  const unsigned short* gah0 = Ah + (size_t)(m0 + rs0) * K + cofs;
  const unsigned short* gah1 = Ah + (size_t)(m0 + rs1) * K + cofs;
  const unsigned short* gal0 = Al + (size_t)(m0 + rs0) * K + cofs;
  const unsigned short* gal1 = Al + (size_t)(m0 + rs1) * K + cofs;
  const unsigned short* gbh0 = Bh + (size_t)(n0 + rs0) * K + cofs;
  const unsigned short* gbh1 = Bh + (size_t)(n0 + rs1) * K + cofs;
  const unsigned short* gbl0 = Bl + (size_t)(n0 + rs0) * K + cofs;
  const unsigned short* gbl1 = Bl + (size_t)(n0 + rs1) * K + cofs;
  unsigned short* lA0 = &Ash[(w * 2 + 0) * 512];
  unsigned short* lA1 = &Ash[(w * 2 + 1) * 512];
  unsigned short* lAl0 = &Asl[(w * 2 + 0) * 512];
  unsigned short* lAl1 = &Asl[(w * 2 + 1) * 512];
  unsigned short* lB0 = &Bsh[(w * 2 + 0) * 512];
  unsigned short* lB1 = &Bsh[(w * 2 + 1) * 512];
  unsigned short* lBl0 = &Bsl[(w * 2 + 0) * 512];
  unsigned short* lBl1 = &Bsl[(w * 2 + 1) * 512];
  for (int k0 = 0; k0 < K; k0 += 32) {
    __syncthreads();
    gll16(gah0 + k0, lA0); gll16(gah1 + k0, lA1);
    gll16(gal0 + k0, lAl0); gll16(gal1 + k0, lAl1);
    gll16(gbh0 + k0, lB0); gll16(gbh1 + k0, lB1);
    gll16(gbl0 + k0, lBl0); gll16(gbl1 + k0, lBl1);
    __syncthreads();
    short8 afh[4], afl[4], bfh[4], bfl[4];
    for (int i = 0; i < 4; ++i) {
      int o = (wm + i * 16 + l15) * 32 + quad * 8;
      afh[i] = *(const short8*)(&Ash[o]);
      afl[i] = *(const short8*)(&Asl[o]);
    }
    for (int j = 0; j < 4; ++j) {
      int o = (wn + j * 16 + l15) * 32 + quad * 8;
      bfh[j] = *(const short8*)(&Bsh[o]);
      bfl[j] = *(const short8*)(&Bsl[o]);
    }
    for (int i = 0; i < 4; ++i)
      for (int j = 0; j < 4; ++j) {
        f32x4 a = acc[i][j];
        a = mfma16(afh[i], bfl[j], a);
        a = mfma16(afl[i], bfh[j], a);
        a = mfma16(afh[i], bfh[j], a);
        acc[i][j] = a;
      }
  }
  // coalesced epilogue through LDS
  __syncthreads();
  unsigned short* eph = &pool2[w * 1152];
  unsigned short* epl = &pool2[4608 + w * 1152];
  int row16 = lane >> 3, chunk = lane & 7;
  for (int i = 0; i < 4; ++i) {
    for (int j = 0; j < 4; ++j) {
      f32x4 a = acc[i][j];
      int lo = j * 16 + l15;
      for (int r = 0; r < 4; ++r) {
        unsigned short hb = f2bf(a[r]);
        eph[(quad * 4 + r) * 72 + lo] = hb;
        epl[(quad * 4 + r) * 72 + lo] = f2bf(a[r] - bf2f(hb));
      }
    }
    for (int it = 0; it < 2; ++it) {
      int rr = it * 8 + row16;
      size_t go = (size_t)(m0 + wm + i * 16 + rr) * NC + n0 + wn + chunk * 8;
      *(u32x4*)(&Ch[go]) = *(const u32x4*)(&eph[rr * 72 + chunk * 8]);
      *(u32x4*)(&Cl[go]) = *(const u32x4*)(&epl[rr * 72 + chunk * 8]);
    }
    __syncthreads();
  }
}

// ---------------- split-bf16 GEMM, MT x 128 tile, f32 output (Wo) --------------------
template<int MT>
__global__ __launch_bounds__(256) void gemm3f(
    const unsigned short* __restrict__ Ah, const unsigned short* __restrict__ Al,
    const unsigned short* __restrict__ Bh, const unsigned short* __restrict__ Bl,
    float* __restrict__ Cf, int N, int K) {
  int m0 = blockIdx.y * MT, n0 = blockIdx.x * 128;
  __shared__ unsigned short pool3[MT * 64 + 8192];
  unsigned short* Ash = pool3;
  unsigned short* Asl = pool3 + MT * 32;
  unsigned short* Bsh = pool3 + MT * 64;
  unsigned short* Bsl = pool3 + MT * 64 + 4096;
  int tid = threadIdx.x;
  int lane = tid & 63, w = tid >> 6;
  int quad = lane >> 4, l15 = lane & 15;
  int wm = (w >> 1) * (MT / 2), wn = (w & 1) * 64;
  constexpr int MI = MT / 32;
  f32x4 acc[MI][4];
  for (int i = 0; i < MI; ++i) for (int j = 0; j < 4; ++j) acc[i][j] = 0;
  constexpr int AI = MT / 64;  // A issues per wave
  int cofs = (lane & 3) * 8;
  const unsigned short* gah[AI]; const unsigned short* gal[AI];
  unsigned short *lAh[AI], *lAl[AI];
  for (int is = 0; is < AI; ++is) {
    int rs = w * (MT / 4) + is * 16 + (lane >> 2);
    gah[is] = Ah + (size_t)(m0 + rs) * K + cofs;
    gal[is] = Al + (size_t)(m0 + rs) * K + cofs;
    lAh[is] = &Ash[(w * AI + is) * 512];
    lAl[is] = &Asl[(w * AI + is) * 512];
  }
  int rsB0 = w * 32 + (lane >> 2), rsB1 = rsB0 + 16;
  const unsigned short* gbh0 = Bh + (size_t)(n0 + rsB0) * K + cofs;
  const unsigned short* gbh1 = Bh + (size_t)(n0 + rsB1) * K + cofs;
  const unsigned short* gbl0 = Bl + (size_t)(n0 + rsB0) * K + cofs;
  const unsigned short* gbl1 = Bl + (size_t)(n0 + rsB1) * K + cofs;
  unsigned short* lB0 = &Bsh[(w * 2 + 0) * 512];
  unsigned short* lB1 = &Bsh[(w * 2 + 1) * 512];
  unsigned short* lBl0 = &Bsl[(w * 2 + 0) * 512];
  unsigned short* lBl1 = &Bsl[(w * 2 + 1) * 512];
  for (int k0 = 0; k0 < K; k0 += 32) {
    __syncthreads();
    for (int is = 0; is < AI; ++is) { gll16(gah[is] + k0, lAh[is]); gll16(gal[is] + k0, lAl[is]); }
    gll16(gbh0 + k0, lB0); gll16(gbh1 + k0, lB1);
    gll16(gbl0 + k0, lBl0); gll16(gbl1 + k0, lBl1);
    __syncthreads();
    short8 afh[MI], afl[MI], bfh[4], bfl[4];
    for (int i = 0; i < MI; ++i) {
      int o = (wm + i * 16 + l15) * 32 + quad * 8;
      afh[i] = *(const short8*)(&Ash[o]);
      afl[i] = *(const short8*)(&Asl[o]);
    }
    for (int j = 0; j < 4; ++j) {
      int o = (wn + j * 16 + l15) * 32 + quad * 8;
      bfh[j] = *(const short8*)(&Bsh[o]);
      bfl[j] = *(const short8*)(&Bsl[o]);
    }
    for (int i = 0; i < MI; ++i)
      for (int j = 0; j < 4; ++j) {
        f32x4 a = acc[i][j];
        a = mfma16(afh[i], bfl[j], a);
        a = mfma16(afl[i], bfh[j], a);
        a = mfma16(afh[i], bfh[j], a);
        acc[i][j] = a;
      }
  }
  // coalesced f32 epilogue through LDS: per-wave 16x64 f32 slab (stride 68)
  __syncthreads();
  float* epf = (float*)(pool3 + w * 2176);
  for (int i = 0; i < MI; ++i) {
    for (int j = 0; j < 4; ++j) {
      f32x4 a = acc[i][j];
      for (int r = 0; r < 4; ++r) epf[(quad * 4 + r) * 68 + j * 16 + l15] = a[r];
    }
    for (int it = 0; it < 4; ++it) {
      int rr = (lane >> 4) + it * 4;
      int ch = lane & 15;
      *(f32x4*)(&Cf[(size_t)(m0 + wm + i * 16 + rr) * N + n0 + wn + ch * 4]) =
          *(const f32x4*)(&epf[rr * 68 + ch * 4]);
    }
    __syncthreads();
  }
}

// ---------------- MoE up, all experts: grid (N/128, E*32) ----------------------------
__global__ __launch_bounds__(256) void moe_up(
    const unsigned short* __restrict__ A, const unsigned short* __restrict__ W1T,
    unsigned short* __restrict__ hmid, int N, int K,
    const int* __restrict__ cnt, const int* __restrict__ offs,
    const int* __restrict__ list, const float* __restrict__ b1) {
  int e = blockIdx.y >> 5, mt = blockIdx.y & 31;
  int M = cnt[e];
  int m0 = mt * 128, n0 = blockIdx.x * 128;
  if (M == 0 || m0 >= M) return;
  const unsigned short* Bt = W1T + (size_t)e * DFF_ * D_;
  const int* liste = list + e * T_;
  const float* bias = b1 + (size_t)e * DFF_;
  size_t obase = (size_t)offs[e];
  __shared__ unsigned short pool[8192];
  unsigned short* As = pool;
  unsigned short* Bs = pool + 4096;
  int tid = threadIdx.x;
  int lane = tid & 63, w = tid >> 6;
  int quad = lane >> 4, l15 = lane & 15;
  int wm = (w >> 1) * 64, wn = (w & 1) * 64;
  f32x4 acc[4][4];
  for (int i = 0; i < 4; ++i) for (int j = 0; j < 4; ++j) acc[i][j] = 0;
  int rs0 = w * 32 + (lane >> 2), rs1 = rs0 + 16;
  int cofs = (lane & 3) * 8;
  const unsigned short* ga0 = A + (size_t)liste[min(m0 + rs0, M - 1)] * K + cofs;
  const unsigned short* ga1 = A + (size_t)liste[min(m0 + rs1, M - 1)] * K + cofs;
  const unsigned short* gb0 = Bt + (size_t)(n0 + rs0) * K + cofs;
  const unsigned short* gb1 = Bt + (size_t)(n0 + rs1) * K + cofs;
  unsigned short* lA0 = &As[(w * 2 + 0) * 512];
  unsigned short* lA1 = &As[(w * 2 + 1) * 512];
  unsigned short* lB0 = &Bs[(w * 2 + 0) * 512];
  unsigned short* lB1 = &Bs[(w * 2 + 1) * 512];
  for (int k0 = 0; k0 < K; k0 += 32) {
    __syncthreads();
    gll16(ga0 + k0, lA0); gll16(ga1 + k0, lA1);
    gll16(gb0 + k0, lB0); gll16(gb1 + k0, lB1);
    __syncthreads();
    short8 af[4], bfr[4];
    for (int i = 0; i < 4; ++i) af[i] = *(const short8*)(&As[(wm + i * 16 + l15) * 32 + quad * 8]);
    for (int j = 0; j < 4; ++j) bfr[j] = *(const short8*)(&Bs[(wn + j * 16 + l15) * 32 + quad * 8]);
    for (int i = 0; i < 4; ++i)
      for (int j = 0; j < 4; ++j)
        acc[i][j] = mfma16(af[i], bfr[j], acc[i][j]);
  }
  // coalesced epilogue through LDS: per-wave 16x64 slab, stride 72
  __syncthreads();
  unsigned short* ep = &pool[w * 1152];
  int row16 = lane >> 3, chunk = lane & 7;
  for (int i = 0; i < 4; ++i) {
    for (int j = 0; j < 4; ++j) {
      f32x4 a = acc[i][j];
      int colg = n0 + wn + j * 16 + l15;
      float bv = bias[colg];
      for (int r = 0; r < 4; ++r)
        ep[(quad * 4 + r) * 72 + j * 16 + l15] = f2bf(gelu_f(a[r] + bv));
    }
    for (int it = 0; it < 2; ++it) {
      int rr = it * 8 + row16;
      int rowg = m0 + wm + i * 16 + rr;
      if (rowg < M)
        *(u32x4*)(&hmid[(obase + rowg) * DFF_ + n0 + wn + chunk * 8]) =
            *(const u32x4*)(&ep[rr * 72 + chunk * 8]);
    }
  }
}

// ---------------- MoE down, all experts: grid (D/128, E*64), atomic accum ------------
__global__ __launch_bounds__(256) void moe_down(
    const unsigned short* __restrict__ hmid, const unsigned short* __restrict__ W2T,
    int N, int K,
    const int* __restrict__ cnt, const int* __restrict__ offs,
    const int* __restrict__ list, const float* __restrict__ gatev,
    const float* __restrict__ b2, float* __restrict__ accum) {
  int e = blockIdx.y >> 6, mt = blockIdx.y & 63;
  int M = cnt[e];
  int m0 = mt * 64, n0 = blockIdx.x * 128;
  if (M == 0 || m0 >= M) return;
  const unsigned short* A = hmid + (size_t)offs[e] * DFF_;
  const unsigned short* Bt = W2T + (size_t)e * D_ * DFF_;
  const int* liste = list + e * T_;
  const float* gv = gatev + e * T_;
  const float* bias = b2 + (size_t)e * D_;
  __shared__ unsigned short As[64 * 32], Bs[128 * 32];
  int tid = threadIdx.x;
  int lane = tid & 63, w = tid >> 6;
  int quad = lane >> 4, l15 = lane & 15;
  int wm = (w >> 1) * 32, wn = (w & 1) * 64;
  f32x4 acc[2][4];
  for (int i = 0; i < 2; ++i) for (int j = 0; j < 4; ++j) acc[i][j] = 0;
  int rsA = w * 16 + (lane >> 2);
  int rsB0 = w * 32 + (lane >> 2), rsB1 = rsB0 + 16;
  int cofs = (lane & 3) * 8;
  const unsigned short* ga = A + (size_t)min(m0 + rsA, M - 1) * K + cofs;
  const unsigned short* gb0 = Bt + (size_t)(n0 + rsB0) * K + cofs;
  const unsigned short* gb1 = Bt + (size_t)(n0 + rsB1) * K + cofs;
  unsigned short* lA = &As[w * 512];
  unsigned short* lB0 = &Bs[(w * 2 + 0) * 512];
  unsigned short* lB1 = &Bs[(w * 2 + 1) * 512];
  for (int k0 = 0; k0 < K; k0 += 32) {
    __syncthreads();
    gll16(ga + k0, lA);
    gll16(gb0 + k0, lB0); gll16(gb1 + k0, lB1);
    __syncthreads();
    short8 af[2], bfr[4];
    for (int i = 0; i < 2; ++i) af[i] = *(const short8*)(&As[(wm + i * 16 + l15) * 32 + quad * 8]);
    for (int j = 0; j < 4; ++j) bfr[j] = *(const short8*)(&Bs[(wn + j * 16 + l15) * 32 + quad * 8]);
    for (int i = 0; i < 2; ++i)
      for (int j = 0; j < 4; ++j)
        acc[i][j] = mfma16(af[i], bfr[j], acc[i][j]);
  }
  for (int i = 0; i < 2; ++i) for (int j = 0; j < 4; ++j) {
    int row = m0 + wm + i * 16 + quad * 4;
    int col = n0 + wn + j * 16 + l15;
    f32x4 a = acc[i][j];
    float bv = bias[col];
    for (int r = 0; r < 4; ++r) if (row + r < M) {
      int tt = liste[row + r];
      float gg = gv[row + r];
      atomicAdd(&accum[(size_t)tt * D_ + col], gg * (a[r] + bv));
    }
  }
}

// ---------------- flash attention, split-bf16, swizzled V^T in LDS -------------------
// VsT pos(d,j) = d*64 + blk*8 + (j&7), blk = ((j>>3)^(d&7) + (d>>3)) & 7
__global__ __launch_bounds__(256) void attn_kernel(
    const unsigned short* __restrict__ qh, const unsigned short* __restrict__ ql,
    const unsigned short* __restrict__ kvh, const unsigned short* __restrict__ kvl,
    unsigned short* __restrict__ avh, unsigned short* __restrict__ avl) {
  int itile = blockIdx.x;
  int bh = blockIdx.y;
  int b = bh & 1, n = bh >> 1;
  __shared__ unsigned short Ksh[64 * 72], Ksl[64 * 72];
  __shared__ unsigned short VsTh[64 * 64], VsTl[64 * 64];
  __shared__ unsigned short Psh[4][16 * 72], Psl[4][16 * 72];
  int tid = threadIdx.x;
  int w = tid >> 6, lane = tid & 63, quad = lane >> 4, l15 = lane & 15;
  int i_base = itile * 64 + w * 16;
  short8 qfh[2], qfl[2];
  {
    size_t qo = ((size_t)((i_base + l15) * B_ + b)) * 1024 + n * 64;
    qfh[0] = *(const short8*)(qh + qo + quad * 8);
    qfh[1] = *(const short8*)(qh + qo + 32 + quad * 8);
    qfl[0] = *(const short8*)(ql + qo + quad * 8);
    qfl[1] = *(const short8*)(ql + qo + 32 + quad * 8);
  }
  float m_i[4], l_i[4];
  f32x4 o[4];
  for (int r = 0; r < 4; ++r) { m_i[r] = -1e30f; l_i[r] = 0.0f; }
  for (int d = 0; d < 4; ++d) o[d] = 0;
  int srow = tid >> 2, sc = tid & 3;
  // V staging lane mapping: j-pair + d-block
  int jl = w * 16 + (lane >> 3) * 2;       // local j (even)
  int d0v = (lane & 7) * 8;
  int jbv = jl >> 3, jwv = jl & 7;
  for (int jt = 0; jt < 32; ++jt) {
    __syncthreads();
    {
      size_t so = ((size_t)((jt * 64 + srow) * B_ + b)) * 2048 + n * 128 + sc * 16;
      int lo = srow * 72 + sc * 16;
      *(short8*)(&Ksh[lo])     = *(const short8*)(kvh + so);
      *(short8*)(&Ksh[lo + 8]) = *(const short8*)(kvh + so + 8);
      *(short8*)(&Ksl[lo])     = *(const short8*)(kvl + so);
      *(short8*)(&Ksl[lo + 8]) = *(const short8*)(kvl + so + 8);
      size_t vo = ((size_t)((jt * 64 + jl) * B_ + b)) * 2048 + n * 128 + 64 + d0v;
      short8 v0h = *(const short8*)(kvh + vo);
      short8 v1h = *(const short8*)(kvh + vo + 4096);
      short8 v0l = *(const short8*)(kvl + vo);
      short8 v1l = *(const short8*)(kvl + vo + 4096);
      for (int jj = 0; jj < 8; ++jj) {
        int d = d0v + jj;
        int blk = ((jbv ^ jj) + (d >> 3)) & 7;    // d&7 == jj
        int pos = d * 64 + blk * 8 + jwv;
        *(unsigned int*)(&VsTh[pos]) =
            (unsigned int)(unsigned short)v0h[jj] | ((unsigned int)(unsigned short)v1h[jj] << 16);
        *(unsigned int*)(&VsTl[pos]) =
            (unsigned int)(unsigned short)v0l[jj] | ((unsigned int)(unsigned short)v1l[jj] << 16);
      }
    }
    __syncthreads();
    f32x4 sac[4];
    for (int t4 = 0; t4 < 4; ++t4) {
      f32x4 a = 0;
      int o0 = (t4 * 16 + l15) * 72 + quad * 8;
      short8 kh0 = *(const short8*)(&Ksh[o0]);
      short8 kh1 = *(const short8*)(&Ksh[o0 + 32]);
      short8 kl0 = *(const short8*)(&Ksl[o0]);
      short8 kl1 = *(const short8*)(&Ksl[o0 + 32]);
      a = mfma16(qfh[0], kl0, a);
      a = mfma16(qfh[1], kl1, a);
      a = mfma16(qfl[0], kh0, a);
      a = mfma16(qfl[1], kh1, a);
      a = mfma16(qfh[0], kh0, a);
      a = mfma16(qfh[1], kh1, a);
      sac[t4] = a;
    }
    float p[4][4];
    float alpha[4];
    for (int r = 0; r < 4; ++r) {
      float m1 = fmaxf(fmaxf(sac[0][r], sac[1][r]), fmaxf(sac[2][r], sac[3][r])) * SCALE_;
      for (int off = 1; off < 16; off <<= 1) m1 = fmaxf(m1, __shfl_xor(m1, off, 16));
      float mnew = fmaxf(m_i[r], m1);
      alpha[r] = __expf(m_i[r] - mnew);
      m_i[r] = mnew;
      float rs = 0.f;
      for (int t4 = 0; t4 < 4; ++t4) {
        float pp = __expf(sac[t4][r] * SCALE_ - mnew);
        p[t4][r] = pp; rs += pp;
      }
      for (int off = 1; off < 16; off <<= 1) rs += __shfl_xor(rs, off, 16);
      l_i[r] = l_i[r] * alpha[r] + rs;
    }
    for (int d = 0; d < 4; ++d) for (int r = 0; r < 4; ++r) o[d][r] *= alpha[r];
    for (int t4 = 0; t4 < 4; ++t4) for (int r = 0; r < 4; ++r) {
      unsigned short hb = f2bf(p[t4][r]);
      int po = (quad * 4 + r) * 72 + t4 * 16 + l15;
      Psh[w][po] = hb;
      Psl[w][po] = f2bf(p[t4][r] - bf2f(hb));
    }
    __syncthreads();
    for (int dblk = 0; dblk < 4; ++dblk) {
      f32x4 a = o[dblk];
      int d = dblk * 16 + l15;
      for (int ks = 0; ks < 2; ++ks) {
        int po = l15 * 72 + ks * 32 + quad * 8;
        short8 pfh = *(const short8*)(&Psh[w][po]);
        short8 pfl = *(const short8*)(&Psl[w][po]);
        int pb = (((ks * 4 + quad) ^ (d & 7)) + (d >> 3)) & 7;
        short8 vfh = *(const short8*)(&VsTh[d * 64 + pb * 8]);
        short8 vfl = *(const short8*)(&VsTl[d * 64 + pb * 8]);
        a = mfma16(pfh, vfl, a);
        a = mfma16(pfl, vfh, a);
        a = mfma16(pfh, vfh, a);
      }
      o[dblk] = a;
    }
  }
  // coalesced epilogue: stage wave's 16x64 O tile in Psh[w]/Psl[w], wide stores
  {
    int row16 = lane >> 3, chunk = lane & 7;
    for (int d = 0; d < 4; ++d) for (int r = 0; r < 4; ++r) {
      float val = o[d][r] / l_i[r];
      unsigned short hb = f2bf(val);
      int po = (quad * 4 + r) * 72 + d * 16 + l15;
      Psh[w][po] = hb;
      Psl[w][po] = f2bf(val - bf2f(hb));
    }
    for (int it = 0; it < 2; ++it) {
      int rr = it * 8 + row16;
      size_t go = ((size_t)((i_base + rr) * B_ + b)) * 1024 + n * 64 + chunk * 8;
      *(u32x4*)(&avh[go]) = *(const u32x4*)(&Psh[w][rr * 72 + chunk * 8]);
      *(u32x4*)(&avl[go]) = *(const u32x4*)(&Psl[w][rr * 72 + chunk * 8]);
    }
  }
}

// ---------------- gating: softmax(x@Wg), top-2, lists + loss stats -------------------
__global__ __launch_bounds__(256) void gate_kernel(const float* __restrict__ x,
    const float* __restrict__ Wg, int* __restrict__ cnt,
    float* __restrict__ me_sum, float* __restrict__ ce_sum,
    int* __restrict__ list, float* __restrict__ gatev) {
  __shared__ float sprob[4][4];
  __shared__ int sidx[4];
  int w = threadIdx.x >> 6, lane = threadIdx.x & 63;
  int t = blockIdx.x * 4 + w;
  f32x4 acc = 0;
  const float* xr = x + (size_t)t * D_;
  for (int j = 0; j < 16; ++j) {
    int d = j * 64 + lane;
    float xd = xr[d];
    f32x4 wg = ((const f32x4*)Wg)[d];
    acc += xd * wg;
  }
  for (int c = 0; c < 4; ++c) {
    float vv = acc[c];
    for (int off = 32; off; off >>= 1) vv += __shfl_xor(vv, off);
    acc[c] = vv;
  }
  if (lane == 0) {
    float p[4];
    float mx = fmaxf(fmaxf(acc[0], acc[1]), fmaxf(acc[2], acc[3]));
    float sum = 0.f;
    for (int e = 0; e < 4; ++e) { p[e] = expf(acc[e] - mx); sum += p[e]; }
    for (int e = 0; e < 4; ++e) p[e] /= sum;
    int i0 = 0;
    for (int e = 1; e < 4; ++e) if (p[e] > p[i0]) i0 = e;
    int i1 = (i0 == 0) ? 1 : 0;
    for (int e = 0; e < 4; ++e) if (e != i0 && p[e] > p[i1]) i1 = e;
    float g0 = p[i0] / (p[i0] + p[i1]);
    float g1 = p[i1] / (p[i0] + p[i1]);
    int pos = atomicAdd(&cnt[i0], 1);
    list[i0 * T_ + pos] = t; gatev[i0 * T_ + pos] = g0;
    pos = atomicAdd(&cnt[i1], 1);
    list[i1 * T_ + pos] = t; gatev[i1 * T_ + pos] = g1;
    for (int e = 0; e < 4; ++e) sprob[w][e] = p[e];
    sidx[w] = i0;
  }
  __syncthreads();
  if (threadIdx.x == 0) {
    float mp[4], cc[4] = {0, 0, 0, 0};
    for (int e = 0; e < 4; ++e) mp[e] = sprob[0][e] + sprob[1][e] + sprob[2][e] + sprob[3][e];
    for (int ww = 0; ww < 4; ++ww) cc[sidx[ww]] += 1.0f;
    for (int e = 0; e < 4; ++e) {
      atomicAdd(&me_sum[e], mp[e]);
      if (cc[e] > 0.f) atomicAdd(&ce_sum[e], cc[e]);
    }
  }
}

__global__ void loss_offs_kernel(const float* __restrict__ me, const float* __restrict__ ce,
                                 const int* __restrict__ cnt, int* __restrict__ offs,
                                 float* __restrict__ out) {
  if (threadIdx.x == 0) {
    float l = 0.f;
    for (int e = 0; e < E_; ++e) l += (me[e] * (1.0f / T_)) * (ce[e] * (1.0f / T_));
    out[0] = (float)E_ * l;
    int o = 0;
    for (int e = 0; e < E_; ++e) { offs[e] = o; o += cnt[e]; }
  }
}

extern "C" void kernel_launch(void* const* d_in, const int* in_sizes, int n_in,
                              void* d_out, int out_size, void* d_ws, size_t ws_size,
                              hipStream_t stream) {
  const float* hid       = (const float*)d_in[0];
  const float* ln_in_g   = (const float*)d_in[1];
  const float* ln_in_b   = (const float*)d_in[2];
  const float* Wq        = (const float*)d_in[3];
  const float* Wkv       = (const float*)d_in[4];
  const float* Wo        = (const float*)d_in[5];
  const float* ln_attn_g = (const float*)d_in[6];
  const float* ln_attn_b = (const float*)d_in[7];
  const float* ln_post_g = (const float*)d_in[8];
  const float* ln_post_b = (const float*)d_in[9];
  const float* Wg        = (const float*)d_in[10];
  const float* W1        = (const float*)d_in[11];
  const float* b1        = (const float*)d_in[12];
  const float* W2        = (const float*)d_in[13];
  const float* b2        = (const float*)d_in[14];
  float* out = (float*)d_out;

  char* p = (char*)d_ws;
  size_t off = 0;
  auto alloc = [&](size_t bytes) -> void* {
    void* r = p + off; off += (bytes + 255) & ~(size_t)255; return r;
  };
  // Overlays (all alloc sizes are multiples of 256 -> regions are exactly contiguous):
  //   hmid_all (64MB, [8192 rows x DFF] bf16) = h+x+qh+ql+hbh+hbl   (all dead by MoE)
  //   attn_out (16MB f32) = qh+ql                                   (dead after attn)
  //   W1T (32MB) = kvh+kvl                                          (dead after attn)
  //   W2T (32MB) = avh..WoTl                                        (dead after Wo gemm)
  float* h        = (float*)alloc((size_t)T_ * D_ * 4);
  float* x        = (float*)alloc((size_t)T_ * D_ * 4);
  unsigned short* hmid_all = (unsigned short*)h;
  unsigned short* qh = (unsigned short*)alloc((size_t)T_ * 1024 * 2);
  unsigned short* ql = (unsigned short*)alloc((size_t)T_ * 1024 * 2);
  float* attn_out = (float*)qh;
  unsigned short* hbh = (unsigned short*)alloc((size_t)T_ * D_ * 2);
  unsigned short* hbl = (unsigned short*)alloc((size_t)T_ * D_ * 2);
  unsigned short* xb  = (unsigned short*)alloc((size_t)T_ * D_ * 2);
  unsigned short* kvh = (unsigned short*)alloc((size_t)T_ * 2048 * 2);
  unsigned short* kvl = (unsigned short*)alloc((size_t)T_ * 2048 * 2);
  unsigned short* W1T = kvh;
  unsigned short* avh = (unsigned short*)alloc((size_t)T_ * 1024 * 2);
  unsigned short* avl = (unsigned short*)alloc((size_t)T_ * 1024 * 2);
  unsigned short* W2T = avh;
  unsigned short* WqTh  = (unsigned short*)alloc((size_t)1024 * 1024 * 2);
  unsigned short* WqTl  = (unsigned short*)alloc((size_t)1024 * 1024 * 2);
  unsigned short* WkvTh = (unsigned short*)alloc((size_t)2048 * 1024 * 2);
  unsigned short* WkvTl = (unsigned short*)alloc((size_t)2048 * 1024 * 2);
  unsigned short* WoTh  = (unsigned short*)alloc((size_t)1024 * 1024 * 2);
  unsigned short* WoTl  = (unsigned short*)alloc((size_t)1024 * 1024 * 2);
  void* ghdr = alloc(256);
  int* cnt = (int*)ghdr;
  float* me_sum = (float*)ghdr + 4;
  float* ce_sum = (float*)ghdr + 8;
  int* offs = (int*)ghdr + 12;
  int* list = (int*)alloc((size_t)E_ * T_ * 4);
  float* gatev = (float*)alloc((size_t)E_ * T_ * 4);

  hipMemsetAsync(ghdr, 0, 64, stream);

  dim3 tb(32, 8);
  transpose_cvt_split<<<dim3(32, 16), tb, 0, stream>>>(Wq, WqTh, WqTl, 1024, 1024);
  transpose_cvt_split<<<dim3(64, 16), tb, 0, stream>>>(Wkv, WkvTh, WkvTl, 1024, 2048);
  transpose_cvt_split<<<dim3(32, 16), tb, 0, stream>>>(Wo, WoTh, WoTl, 1024, 1024);

  ln_in_kernel<<<T_, 256, 0, stream>>>(hid, ln_in_g, ln_in_b, h, hbh, hbl);

  qkv_gemm<<<dim3(24, 32), 256, 0, stream>>>(hbh, hbl, WqTh, WqTl, WkvTh, WkvTl,
      qh, ql, kvh, kvl);

  attn_kernel<<<dim3(32, 32), 256, 0, stream>>>(qh, ql, kvh, kvl, avh, avl);

  gemm3f<64><<<dim3(8, 64), 256, 0, stream>>>(avh, avl, WoTh, WoTl, attn_out, 1024, 1024);

  ln_fused_kernel<<<T_, 256, 0, stream>>>(hid, h, attn_out, ln_attn_g, ln_attn_b,
      ln_post_g, ln_post_b, out, x, xb);

  gate_kernel<<<T_ / 4, 256, 0, stream>>>(x, Wg, cnt, me_sum, ce_sum, list, gatev);
  loss_offs_kernel<<<1, 64, 0, stream>>>(me_sum, ce_sum, cnt, offs, out + (size_t)T_ * D_);

  transpose_cvt<<<dim3(128, 16, 4), tb, 0, stream>>>(W1, W1T, 1024, 4096);
  transpose_cvt<<<dim3(32, 64, 4), tb, 0, stream>>>(W2, W2T, 4096, 1024);

  moe_up<<<dim3(32, 128), 256, 0, stream>>>(xb, W1T, hmid_all, DFF_, 1024,
      cnt, offs, list, b1);
  moe_down<<<dim3(8, 256), 256, 0, stream>>>(hmid_all, W2T, D_, DFF_,
      cnt, offs, list, gatev, b2, out);
}